// Round 3
// baseline (1184.880 us; speedup 1.0000x reference)
//
#include <hip/hip_runtime.h>

#define EMB 64
#define HID 128
#define BONDF 16
#define ATOMF 32

// ---------------- embedding: h = x @ Wemb.T ----------------
__global__ __launch_bounds__(256) void embed_kernel(
    const float* __restrict__ x, const float* __restrict__ Wemb,
    float* __restrict__ h, int N)
{
  __shared__ float sW[EMB * ATOMF];
  int tid = threadIdx.x;
  for (int i = tid; i < EMB * ATOMF; i += 256) sW[i] = Wemb[i];
  __syncthreads();
  int row = blockIdx.x * 256 + tid;
  if (row >= N) return;
  float xin[ATOMF];
  const float4* xr = reinterpret_cast<const float4*>(x + (size_t)row * ATOMF);
#pragma unroll
  for (int k4 = 0; k4 < ATOMF / 4; ++k4) {
    float4 v = xr[k4];
    xin[4 * k4 + 0] = v.x; xin[4 * k4 + 1] = v.y;
    xin[4 * k4 + 2] = v.z; xin[4 * k4 + 3] = v.w;
  }
  float4* hr = reinterpret_cast<float4*>(h + (size_t)row * EMB);
  for (int o4 = 0; o4 < EMB / 4; ++o4) {
    float acc[4];
#pragma unroll
    for (int c = 0; c < 4; ++c) {
      const float* wrow = sW + (o4 * 4 + c) * ATOMF;
      float a = 0.f;
#pragma unroll
      for (int kk = 0; kk < ATOMF / 4; ++kk) {
        float4 w = reinterpret_cast<const float4*>(wrow)[kk];
        a = fmaf(w.x, xin[4 * kk + 0], a);
        a = fmaf(w.y, xin[4 * kk + 1], a);
        a = fmaf(w.z, xin[4 * kk + 2], a);
        a = fmaf(w.w, xin[4 * kk + 3], a);
      }
      acc[c] = a;
    }
    hr[o4] = make_float4(acc[0], acc[1], acc[2], acc[3]);
  }
}

// ------------- histogram of dst + scatter of edge_attr (once/call) -------------
__global__ __launch_bounds__(256) void hist_kernel(
    const int* __restrict__ ei, const float* __restrict__ ea,
    float* __restrict__ S_ea, int* __restrict__ deg, int E)
{
  long long idx = (long long)blockIdx.x * 256 + threadIdx.x;
  if (idx >= (long long)E * BONDF) return;
  int e = (int)(idx >> 4), f = (int)(idx & 15);
  int d = ei[E + e];  // dst = edge_index[1][e]
  atomicAdd(&S_ea[(size_t)d * BONDF + f], ea[idx]);
  if (f == 0) atomicAdd(&deg[d], 1);
}

// ------------- single-block exclusive scan of deg -> off (once/call) -------------
__global__ __launch_bounds__(256) void scan_kernel(
    const int* __restrict__ deg, int* __restrict__ off, int n)
{
  __shared__ int warpsums[4];
  __shared__ int s_carry;
  int tid = threadIdx.x, lane = tid & 63, wid = tid >> 6;
  if (tid == 0) s_carry = 0;
  __syncthreads();
  for (int base = 0; base < n; base += 256) {
    int i = base + tid;
    int v = (i < n) ? deg[i] : 0;
    int x = v;
#pragma unroll
    for (int d = 1; d < 64; d <<= 1) {
      int t = __shfl_up(x, d, 64);
      if (lane >= d) x += t;
    }
    if (lane == 63) warpsums[wid] = x;
    __syncthreads();  // warpsums visible
    int wsum = 0;
    for (int w = 0; w < wid; ++w) wsum += warpsums[w];
    int incl = x + wsum + s_carry;
    if (i < n) off[i] = incl - v;  // exclusive
    __syncthreads();  // all reads of warpsums/s_carry done
    if (tid == 255) s_carry = incl;
    __syncthreads();  // carry visible for next chunk
  }
  if (tid == 0) off[n] = s_carry;
}

// ------------- place edges into CSR slots (once/call) -------------
__global__ __launch_bounds__(256) void place_kernel(
    const int* __restrict__ ei, const int* __restrict__ off,
    int* __restrict__ cursor, int* __restrict__ csr_src, int E)
{
  int e = blockIdx.x * 256 + threadIdx.x;
  if (e >= E) return;
  int d = ei[E + e];
  int pos = atomicAdd(&cursor[d], 1);
  csr_src[off[d] + pos] = ei[e];  // src = edge_index[0][e]
}

// ------------- per-layer: aggr[i] = h[i] + sum_{e->i} h[src[e]] -------------
__global__ __launch_bounds__(256) void aggregate_kernel(
    const float* __restrict__ h, const int* __restrict__ off,
    const int* __restrict__ csr_src, float* __restrict__ aggr, int N)
{
  int lane = threadIdx.x & 63;
  int node = blockIdx.x * 4 + (threadIdx.x >> 6);
  if (node >= N) return;
  float acc = h[(size_t)node * EMB + lane];  // self loop
  int s0 = off[node], s1 = off[node + 1];
  int e = s0;
  for (; e + 1 < s1; e += 2) {
    int a = csr_src[e], b = csr_src[e + 1];
    float va = h[(size_t)a * EMB + lane];
    float vb = h[(size_t)b * EMB + lane];
    acc += va;
    acc += vb;
  }
  if (e < s1) acc += h[(size_t)csr_src[e] * EMB + lane];
  aggr[(size_t)node * EMB + lane] = acc;
}

// ------------- per-layer fused MLP (edge-emb term + 2 GEMVs), pre-BN out -------------
__global__ __launch_bounds__(256) void mlp_kernel(
    const float* __restrict__ aggr, const float* __restrict__ S_ea,
    const int* __restrict__ deg,
    const float* __restrict__ W1, const float* __restrict__ b1,
    const float* __restrict__ W2, const float* __restrict__ We,
    const float* __restrict__ be, float* __restrict__ tmp, int N)
{
  __shared__ float sW1[HID * EMB];
  __shared__ float sW2t[HID * EMB];  // transposed: [j][o]
  __shared__ float sWe[EMB * BONDF];
  __shared__ float sb1[HID];
  __shared__ float sbe[EMB];
  int tid = threadIdx.x;
  for (int i = tid; i < HID * EMB; i += 256) sW1[i] = W1[i];
  for (int i = tid; i < HID * EMB; i += 256) {
    int o = i >> 7, j = i & 127;
    sW2t[j * EMB + o] = W2[i];
  }
  for (int i = tid; i < EMB * BONDF; i += 256) sWe[i] = We[i];
  if (tid < HID) sb1[tid] = b1[tid];
  if (tid < EMB) sbe[tid] = be[tid];
  __syncthreads();
  int row = blockIdx.x * 256 + tid;
  if (row >= N) return;

  float ea[BONDF];
  const float4* er = reinterpret_cast<const float4*>(S_ea + (size_t)row * BONDF);
#pragma unroll
  for (int i = 0; i < BONDF / 4; ++i) {
    float4 v = er[i];
    ea[4 * i + 0] = v.x; ea[4 * i + 1] = v.y;
    ea[4 * i + 2] = v.z; ea[4 * i + 3] = v.w;
  }
  float dp1 = (float)deg[row] + 1.0f;

  float in[EMB];
  const float4* ar = reinterpret_cast<const float4*>(aggr + (size_t)row * EMB);
#pragma unroll
  for (int k4 = 0; k4 < EMB / 4; ++k4) {
    float4 v = ar[k4];
    in[4 * k4 + 0] = v.x; in[4 * k4 + 1] = v.y;
    in[4 * k4 + 2] = v.z; in[4 * k4 + 3] = v.w;
  }
  // in += S_ea @ We.T + (deg+1)*be
#pragma unroll 4
  for (int k = 0; k < EMB; ++k) {
    float a = in[k] + sbe[k] * dp1;
    const float* wr = sWe + k * BONDF;
#pragma unroll
    for (int f = 0; f < BONDF; ++f) a = fmaf(wr[f], ea[f], a);
    in[k] = a;
  }

  float hn[EMB];
#pragma unroll
  for (int o = 0; o < EMB; ++o) hn[o] = 0.f;
#pragma unroll 2
  for (int j = 0; j < HID; ++j) {
    float hj = sb1[j];
    const float4* w1r = reinterpret_cast<const float4*>(sW1 + j * EMB);
#pragma unroll
    for (int kk = 0; kk < EMB / 4; ++kk) {
      float4 w = w1r[kk];
      hj = fmaf(w.x, in[4 * kk + 0], hj);
      hj = fmaf(w.y, in[4 * kk + 1], hj);
      hj = fmaf(w.z, in[4 * kk + 2], hj);
      hj = fmaf(w.w, in[4 * kk + 3], hj);
    }
    hj = fmaxf(hj, 0.f);
    const float4* w2r = reinterpret_cast<const float4*>(sW2t + j * EMB);
#pragma unroll
    for (int oo = 0; oo < EMB / 4; ++oo) {
      float4 w = w2r[oo];
      hn[4 * oo + 0] = fmaf(w.x, hj, hn[4 * oo + 0]);
      hn[4 * oo + 1] = fmaf(w.y, hj, hn[4 * oo + 1]);
      hn[4 * oo + 2] = fmaf(w.z, hj, hn[4 * oo + 2]);
      hn[4 * oo + 3] = fmaf(w.w, hj, hn[4 * oo + 3]);
    }
  }
  // note: b2 omitted -- it cancels exactly in BatchNorm (constant column shift)
  float4* tr = reinterpret_cast<float4*>(tmp + (size_t)row * EMB);
#pragma unroll
  for (int o4 = 0; o4 < EMB / 4; ++o4)
    tr[o4] = make_float4(hn[4 * o4 + 0], hn[4 * o4 + 1], hn[4 * o4 + 2], hn[4 * o4 + 3]);
}

// ------------- per-layer column stats (sum, sumsq) -------------
__global__ __launch_bounds__(256) void stats_kernel(
    const float* __restrict__ tmp, float* __restrict__ gsums, int N)
{
  __shared__ float sh[256], sh2[256];
  int tid = threadIdx.x;
  int c = tid & 63, rg = tid >> 6;
  float s = 0.f, s2 = 0.f;
  for (int r = blockIdx.x * 4 + rg; r < N; r += gridDim.x * 4) {
    float v = tmp[(size_t)r * EMB + c];
    s += v; s2 += v * v;
  }
  sh[tid] = s; sh2[tid] = s2;
  __syncthreads();
  if (tid < 64) {
    s = sh[tid] + sh[tid + 64] + sh[tid + 128] + sh[tid + 192];
    s2 = sh2[tid] + sh2[tid + 64] + sh2[tid + 128] + sh2[tid + 192];
    atomicAdd(&gsums[c], s);
    atomicAdd(&gsums[EMB + c], s2);
  }
}

// ------------- per-layer BN + (mish) -------------
__global__ __launch_bounds__(256) void bn_kernel(
    const float* __restrict__ tmp, const float* __restrict__ gsums,
    const float* __restrict__ gamma, const float* __restrict__ beta,
    float* __restrict__ out, int N, int apply_mish)
{
  int idx = blockIdx.x * 256 + threadIdx.x;  // float4 index
  int total = N * (EMB / 4);
  if (idx >= total) return;
  int c4 = idx & (EMB / 4 - 1);
  float invN = 1.0f / (float)N;
  float4 v = reinterpret_cast<const float4*>(tmp)[idx];
  float o[4] = {v.x, v.y, v.z, v.w};
#pragma unroll
  for (int c = 0; c < 4; ++c) {
    int col = c4 * 4 + c;
    float mu = gsums[col] * invN;
    float var = gsums[EMB + col] * invN - mu * mu;
    float sc = gamma[col] * rsqrtf(var + 1e-5f);
    float shf = beta[col] - mu * sc;
    float y = o[c] * sc + shf;
    if (apply_mish) {
      float sp = (y > 20.f) ? y : log1pf(expf(y));
      y = y * tanhf(sp);
    }
    o[c] = y;
  }
  reinterpret_cast<float4*>(out)[idx] = make_float4(o[0], o[1], o[2], o[3]);
}

extern "C" void kernel_launch(void* const* d_in, const int* in_sizes, int n_in,
                              void* d_out, int out_size, void* d_ws, size_t ws_size,
                              hipStream_t stream) {
  (void)n_in; (void)out_size; (void)ws_size;
  const float* x     = (const float*)d_in[0];
  const float* ea    = (const float*)d_in[1];
  const float* Wemb  = (const float*)d_in[2];
  const float* W1    = (const float*)d_in[3];
  const float* b1    = (const float*)d_in[4];
  const float* W2    = (const float*)d_in[5];
  // d_in[6] = b2: cancels under BatchNorm, unused
  const float* We    = (const float*)d_in[7];
  const float* be    = (const float*)d_in[8];
  const float* gamma = (const float*)d_in[9];
  const float* beta  = (const float*)d_in[10];
  const int*   ei    = (const int*)d_in[11];

  int N = in_sizes[0] / ATOMF;
  int E = in_sizes[11] / 2;
  int L = in_sizes[3] / (HID * EMB);

  char* w = (char*)d_ws;
  auto alloc = [&](size_t bytes) {
    void* p = (void*)w;
    w += (bytes + 255) & ~(size_t)255;
    return p;
  };
  float* h      = (float*)alloc((size_t)N * EMB * 4);
  float* aggr   = (float*)alloc((size_t)N * EMB * 4);
  float* tmp    = (float*)alloc((size_t)N * EMB * 4);
  float* S_ea   = (float*)alloc((size_t)N * BONDF * 4);
  int*   deg    = (int*)alloc((size_t)N * 4);
  int*   off    = (int*)alloc((size_t)(N + 1) * 4);
  int*   cursor = (int*)alloc((size_t)N * 4);
  int*   csr    = (int*)alloc((size_t)E * 4);
  float* gsums  = (float*)alloc(2 * EMB * 4);

  hipMemsetAsync(S_ea, 0, (size_t)N * BONDF * 4, stream);
  hipMemsetAsync(deg, 0, (size_t)N * 4, stream);
  hipMemsetAsync(cursor, 0, (size_t)N * 4, stream);

  long long tot = (long long)E * BONDF;
  hist_kernel<<<(int)((tot + 255) / 256), 256, 0, stream>>>(ei, ea, S_ea, deg, E);
  scan_kernel<<<1, 256, 0, stream>>>(deg, off, N);
  place_kernel<<<(E + 255) / 256, 256, 0, stream>>>(ei, off, cursor, csr, E);
  embed_kernel<<<(N + 255) / 256, 256, 0, stream>>>(x, Wemb, h, N);

  for (int l = 0; l < L; ++l) {
    aggregate_kernel<<<(N + 3) / 4, 256, 0, stream>>>(h, off, csr, aggr, N);
    mlp_kernel<<<(N + 255) / 256, 256, 0, stream>>>(
        aggr, S_ea, deg,
        W1 + (size_t)l * HID * EMB, b1 + (size_t)l * HID,
        W2 + (size_t)l * HID * EMB, We + (size_t)l * EMB * BONDF,
        be + (size_t)l * EMB, tmp, N);
    hipMemsetAsync(gsums, 0, 2 * EMB * 4, stream);
    stats_kernel<<<512, 256, 0, stream>>>(tmp, gsums, N);
    float* outp = (l == L - 1) ? (float*)d_out : h;
    bn_kernel<<<(N * (EMB / 4) + 255) / 256, 256, 0, stream>>>(
        tmp, gsums, gamma + (size_t)l * EMB, beta + (size_t)l * EMB,
        outp, N, (l < L - 1) ? 1 : 0);
  }
}

// Round 4
// 1073.282 us; speedup vs baseline: 1.1040x; 1.1040x over previous
//
#include <hip/hip_runtime.h>

#define EMB 64
#define HID 128
#define BONDF 16
#define ATOMF 32

// ---------------- embedding: h = x @ Wemb.T ----------------
__global__ __launch_bounds__(256) void embed_kernel(
    const float* __restrict__ x, const float* __restrict__ Wemb,
    float* __restrict__ h, int N)
{
  __shared__ float sW[EMB * ATOMF];
  int tid = threadIdx.x;
  for (int i = tid; i < EMB * ATOMF; i += 256) sW[i] = Wemb[i];
  __syncthreads();
  int row = blockIdx.x * 256 + tid;
  if (row >= N) return;
  float xin[ATOMF];
  const float4* xr = reinterpret_cast<const float4*>(x + (size_t)row * ATOMF);
#pragma unroll
  for (int k4 = 0; k4 < ATOMF / 4; ++k4) {
    float4 v = xr[k4];
    xin[4 * k4 + 0] = v.x; xin[4 * k4 + 1] = v.y;
    xin[4 * k4 + 2] = v.z; xin[4 * k4 + 3] = v.w;
  }
  float4* hr = reinterpret_cast<float4*>(h + (size_t)row * EMB);
  for (int o4 = 0; o4 < EMB / 4; ++o4) {
    float acc[4];
#pragma unroll
    for (int c = 0; c < 4; ++c) {
      const float* wrow = sW + (o4 * 4 + c) * ATOMF;
      float a = 0.f;
#pragma unroll
      for (int kk = 0; kk < ATOMF / 4; ++kk) {
        float4 w = reinterpret_cast<const float4*>(wrow)[kk];
        a = fmaf(w.x, xin[4 * kk + 0], a);
        a = fmaf(w.y, xin[4 * kk + 1], a);
        a = fmaf(w.z, xin[4 * kk + 2], a);
        a = fmaf(w.w, xin[4 * kk + 3], a);
      }
      acc[c] = a;
    }
    hr[o4] = make_float4(acc[0], acc[1], acc[2], acc[3]);
  }
}

// ------------- degree histogram (once/call): one int atomic per edge -------------
__global__ __launch_bounds__(256) void deg_kernel(
    const int* __restrict__ ei, int* __restrict__ deg, int E)
{
  int e = blockIdx.x * 256 + threadIdx.x;
  if (e < E) atomicAdd(&deg[ei[E + e]], 1);
}

// ------------- hierarchical scan phase 1: per-block local exclusive scan -------------
// writes off[i] = local exclusive scan within 256-chunk; bsum[b] = chunk total
__global__ __launch_bounds__(256) void scan1_kernel(
    const int* __restrict__ deg, int* __restrict__ off,
    int* __restrict__ bsum, int n)
{
  __shared__ int ws[4];
  int tid = threadIdx.x, lane = tid & 63, wid = tid >> 6;
  int i = blockIdx.x * 256 + tid;
  int v = (i < n) ? deg[i] : 0;
  int x = v;
#pragma unroll
  for (int d = 1; d < 64; d <<= 1) {
    int t = __shfl_up(x, d, 64);
    if (lane >= d) x += t;
  }
  if (lane == 63) ws[wid] = x;
  __syncthreads();
  int add = 0;
  for (int w = 0; w < wid; ++w) add += ws[w];
  if (i < n) off[i] = x + add - v;  // local exclusive
  if (tid == 255) bsum[blockIdx.x] = x + add;  // chunk total
}

// ------------- phase 2: small exclusive scan (carry-loop, n<=few hundred) -------------
__global__ __launch_bounds__(256) void scan_small_kernel(
    const int* __restrict__ deg, int* __restrict__ off, int n)
{
  __shared__ int warpsums[4];
  __shared__ int s_carry;
  int tid = threadIdx.x, lane = tid & 63, wid = tid >> 6;
  if (tid == 0) s_carry = 0;
  __syncthreads();
  for (int base = 0; base < n; base += 256) {
    int i = base + tid;
    int v = (i < n) ? deg[i] : 0;
    int x = v;
#pragma unroll
    for (int d = 1; d < 64; d <<= 1) {
      int t = __shfl_up(x, d, 64);
      if (lane >= d) x += t;
    }
    if (lane == 63) warpsums[wid] = x;
    __syncthreads();
    int wsum = 0;
    for (int w = 0; w < wid; ++w) wsum += warpsums[w];
    int incl = x + wsum + s_carry;
    if (i < n) off[i] = incl - v;
    __syncthreads();
    if (tid == 255) s_carry = incl;
    __syncthreads();
  }
  if (tid == 0) off[n] = s_carry;
}

// ------------- phase 3: add block offsets; publish off[n] -------------
__global__ __launch_bounds__(256) void scan3_kernel(
    int* __restrict__ off, const int* __restrict__ boff, int n)
{
  int i = blockIdx.x * 256 + threadIdx.x;
  if (i < n) off[i] += boff[blockIdx.x];
  if (i == 0) off[n] = boff[gridDim.x];  // boff[nb] = grand total
}

// ------------- place edges into CSR slots (src + edge id) -------------
__global__ __launch_bounds__(256) void place_kernel(
    const int* __restrict__ ei, const int* __restrict__ off,
    int* __restrict__ cursor, int* __restrict__ csr_src,
    int* __restrict__ csr_eid, int E)
{
  int e = blockIdx.x * 256 + threadIdx.x;
  if (e >= E) return;
  int d = ei[E + e];
  int pos = atomicAdd(&cursor[d], 1);
  int slot = off[d] + pos;
  csr_src[slot] = ei[e];  // src = edge_index[0][e]
  csr_eid[slot] = e;
}

// ------------- S_ea[i] = sum_{e->i} edge_attr[e]  (gather, no atomics) -------------
__global__ __launch_bounds__(256) void gather_ea_kernel(
    const float* __restrict__ ea, const int* __restrict__ off,
    const int* __restrict__ csr_eid, float* __restrict__ S_ea, int N)
{
  int f = threadIdx.x & 15;
  int node = blockIdx.x * 16 + (threadIdx.x >> 4);
  if (node >= N) return;
  float acc = 0.f;
  int s0 = off[node], s1 = off[node + 1];
  for (int e = s0; e < s1; ++e)
    acc += ea[(size_t)csr_eid[e] * BONDF + f];
  S_ea[(size_t)node * BONDF + f] = acc;
}

// ------------- per-layer: aggr[i] = h[i] + sum_{e->i} h[src[e]] -------------
__global__ __launch_bounds__(256) void aggregate_kernel(
    const float* __restrict__ h, const int* __restrict__ off,
    const int* __restrict__ csr_src, float* __restrict__ aggr, int N)
{
  int lane = threadIdx.x & 63;
  int node = blockIdx.x * 4 + (threadIdx.x >> 6);
  if (node >= N) return;
  float acc = h[(size_t)node * EMB + lane];  // self loop
  int s0 = off[node], s1 = off[node + 1];
  int e = s0;
  for (; e + 1 < s1; e += 2) {
    int a = csr_src[e], b = csr_src[e + 1];
    float va = h[(size_t)a * EMB + lane];
    float vb = h[(size_t)b * EMB + lane];
    acc += va;
    acc += vb;
  }
  if (e < s1) acc += h[(size_t)csr_src[e] * EMB + lane];
  aggr[(size_t)node * EMB + lane] = acc;
}

// ------------- per-layer fused MLP (edge-emb term + 2 GEMVs), pre-BN out -------------
__global__ __launch_bounds__(256) void mlp_kernel(
    const float* __restrict__ aggr, const float* __restrict__ S_ea,
    const int* __restrict__ deg,
    const float* __restrict__ W1, const float* __restrict__ b1,
    const float* __restrict__ W2, const float* __restrict__ We,
    const float* __restrict__ be, float* __restrict__ tmp, int N)
{
  __shared__ float sW1[HID * EMB];
  __shared__ float sW2t[HID * EMB];  // transposed: [j][o]
  __shared__ float sWe[EMB * BONDF];
  __shared__ float sb1[HID];
  __shared__ float sbe[EMB];
  int tid = threadIdx.x;
  for (int i = tid; i < HID * EMB; i += 256) sW1[i] = W1[i];
  for (int i = tid; i < HID * EMB; i += 256) {
    int o = i >> 7, j = i & 127;
    sW2t[j * EMB + o] = W2[i];
  }
  for (int i = tid; i < EMB * BONDF; i += 256) sWe[i] = We[i];
  if (tid < HID) sb1[tid] = b1[tid];
  if (tid < EMB) sbe[tid] = be[tid];
  __syncthreads();
  int row = blockIdx.x * 256 + tid;
  if (row >= N) return;

  float ea[BONDF];
  const float4* er = reinterpret_cast<const float4*>(S_ea + (size_t)row * BONDF);
#pragma unroll
  for (int i = 0; i < BONDF / 4; ++i) {
    float4 v = er[i];
    ea[4 * i + 0] = v.x; ea[4 * i + 1] = v.y;
    ea[4 * i + 2] = v.z; ea[4 * i + 3] = v.w;
  }
  float dp1 = (float)deg[row] + 1.0f;

  float in[EMB];
  const float4* ar = reinterpret_cast<const float4*>(aggr + (size_t)row * EMB);
#pragma unroll
  for (int k4 = 0; k4 < EMB / 4; ++k4) {
    float4 v = ar[k4];
    in[4 * k4 + 0] = v.x; in[4 * k4 + 1] = v.y;
    in[4 * k4 + 2] = v.z; in[4 * k4 + 3] = v.w;
  }
  // in += S_ea @ We.T + (deg+1)*be
#pragma unroll 4
  for (int k = 0; k < EMB; ++k) {
    float a = in[k] + sbe[k] * dp1;
    const float* wr = sWe + k * BONDF;
#pragma unroll
    for (int f = 0; f < BONDF; ++f) a = fmaf(wr[f], ea[f], a);
    in[k] = a;
  }

  float hn[EMB];
#pragma unroll
  for (int o = 0; o < EMB; ++o) hn[o] = 0.f;
#pragma unroll 2
  for (int j = 0; j < HID; ++j) {
    float hj = sb1[j];
    const float4* w1r = reinterpret_cast<const float4*>(sW1 + j * EMB);
#pragma unroll
    for (int kk = 0; kk < EMB / 4; ++kk) {
      float4 w = w1r[kk];
      hj = fmaf(w.x, in[4 * kk + 0], hj);
      hj = fmaf(w.y, in[4 * kk + 1], hj);
      hj = fmaf(w.z, in[4 * kk + 2], hj);
      hj = fmaf(w.w, in[4 * kk + 3], hj);
    }
    hj = fmaxf(hj, 0.f);
    const float4* w2r = reinterpret_cast<const float4*>(sW2t + j * EMB);
#pragma unroll
    for (int oo = 0; oo < EMB / 4; ++oo) {
      float4 w = w2r[oo];
      hn[4 * oo + 0] = fmaf(w.x, hj, hn[4 * oo + 0]);
      hn[4 * oo + 1] = fmaf(w.y, hj, hn[4 * oo + 1]);
      hn[4 * oo + 2] = fmaf(w.z, hj, hn[4 * oo + 2]);
      hn[4 * oo + 3] = fmaf(w.w, hj, hn[4 * oo + 3]);
    }
  }
  // note: b2 omitted -- it cancels exactly in BatchNorm (constant column shift)
  float4* tr = reinterpret_cast<float4*>(tmp + (size_t)row * EMB);
#pragma unroll
  for (int o4 = 0; o4 < EMB / 4; ++o4)
    tr[o4] = make_float4(hn[4 * o4 + 0], hn[4 * o4 + 1], hn[4 * o4 + 2], hn[4 * o4 + 3]);
}

// ------------- per-layer column stats (sum, sumsq) -------------
__global__ __launch_bounds__(256) void stats_kernel(
    const float* __restrict__ tmp, float* __restrict__ gsums, int N)
{
  __shared__ float sh[256], sh2[256];
  int tid = threadIdx.x;
  int c = tid & 63, rg = tid >> 6;
  float s = 0.f, s2 = 0.f;
  for (int r = blockIdx.x * 4 + rg; r < N; r += gridDim.x * 4) {
    float v = tmp[(size_t)r * EMB + c];
    s += v; s2 += v * v;
  }
  sh[tid] = s; sh2[tid] = s2;
  __syncthreads();
  if (tid < 64) {
    s = sh[tid] + sh[tid + 64] + sh[tid + 128] + sh[tid + 192];
    s2 = sh2[tid] + sh2[tid + 64] + sh2[tid + 128] + sh2[tid + 192];
    atomicAdd(&gsums[c], s);
    atomicAdd(&gsums[EMB + c], s2);
  }
}

// ------------- per-layer BN + (mish) -------------
__global__ __launch_bounds__(256) void bn_kernel(
    const float* __restrict__ tmp, const float* __restrict__ gsums,
    const float* __restrict__ gamma, const float* __restrict__ beta,
    float* __restrict__ out, int N, int apply_mish)
{
  int idx = blockIdx.x * 256 + threadIdx.x;  // float4 index
  int total = N * (EMB / 4);
  if (idx >= total) return;
  int c4 = idx & (EMB / 4 - 1);
  float invN = 1.0f / (float)N;
  float4 v = reinterpret_cast<const float4*>(tmp)[idx];
  float o[4] = {v.x, v.y, v.z, v.w};
#pragma unroll
  for (int c = 0; c < 4; ++c) {
    int col = c4 * 4 + c;
    float mu = gsums[col] * invN;
    float var = gsums[EMB + col] * invN - mu * mu;
    float sc = gamma[col] * rsqrtf(var + 1e-5f);
    float shf = beta[col] - mu * sc;
    float y = o[c] * sc + shf;
    if (apply_mish) {
      float sp = (y > 20.f) ? y : log1pf(expf(y));
      y = y * tanhf(sp);
    }
    o[c] = y;
  }
  reinterpret_cast<float4*>(out)[idx] = make_float4(o[0], o[1], o[2], o[3]);
}

extern "C" void kernel_launch(void* const* d_in, const int* in_sizes, int n_in,
                              void* d_out, int out_size, void* d_ws, size_t ws_size,
                              hipStream_t stream) {
  (void)n_in; (void)out_size; (void)ws_size;
  const float* x     = (const float*)d_in[0];
  const float* ea    = (const float*)d_in[1];
  const float* Wemb  = (const float*)d_in[2];
  const float* W1    = (const float*)d_in[3];
  const float* b1    = (const float*)d_in[4];
  const float* W2    = (const float*)d_in[5];
  // d_in[6] = b2: cancels under BatchNorm, unused
  const float* We    = (const float*)d_in[7];
  const float* be    = (const float*)d_in[8];
  const float* gamma = (const float*)d_in[9];
  const float* beta  = (const float*)d_in[10];
  const int*   ei    = (const int*)d_in[11];

  int N = in_sizes[0] / ATOMF;
  int E = in_sizes[11] / 2;
  int L = in_sizes[3] / (HID * EMB);

  char* w = (char*)d_ws;
  auto alloc = [&](size_t bytes) {
    void* p = (void*)w;
    w += (bytes + 255) & ~(size_t)255;
    return p;
  };
  float* h      = (float*)alloc((size_t)N * EMB * 4);
  float* aggr   = (float*)alloc((size_t)N * EMB * 4);
  float* tmp    = (float*)alloc((size_t)N * EMB * 4);
  float* S_ea   = (float*)alloc((size_t)N * BONDF * 4);
  int*   deg    = (int*)alloc((size_t)N * 4);
  int*   off    = (int*)alloc((size_t)(N + 1) * 4);
  int*   cursor = (int*)alloc((size_t)N * 4);
  int*   csr    = (int*)alloc((size_t)E * 4);
  int*   csre   = (int*)alloc((size_t)E * 4);
  int*   bsum   = (int*)alloc(1024 * 4);
  int*   boff   = (int*)alloc(1025 * 4);
  float* gsums  = (float*)alloc(2 * EMB * 4);

  hipMemsetAsync(deg, 0, (size_t)N * 4, stream);
  hipMemsetAsync(cursor, 0, (size_t)N * 4, stream);

  int nb = (N + 255) / 256;
  deg_kernel<<<(E + 255) / 256, 256, 0, stream>>>(ei, deg, E);
  scan1_kernel<<<nb, 256, 0, stream>>>(deg, off, bsum, N);
  scan_small_kernel<<<1, 256, 0, stream>>>(bsum, boff, nb);
  scan3_kernel<<<nb, 256, 0, stream>>>(off, boff, N);
  place_kernel<<<(E + 255) / 256, 256, 0, stream>>>(ei, off, cursor, csr, csre, E);
  gather_ea_kernel<<<(N + 15) / 16, 256, 0, stream>>>(ea, off, csre, S_ea, N);
  embed_kernel<<<(N + 255) / 256, 256, 0, stream>>>(x, Wemb, h, N);

  for (int l = 0; l < L; ++l) {
    aggregate_kernel<<<(N + 3) / 4, 256, 0, stream>>>(h, off, csr, aggr, N);
    mlp_kernel<<<(N + 255) / 256, 256, 0, stream>>>(
        aggr, S_ea, deg,
        W1 + (size_t)l * HID * EMB, b1 + (size_t)l * HID,
        W2 + (size_t)l * HID * EMB, We + (size_t)l * EMB * BONDF,
        be + (size_t)l * EMB, tmp, N);
    hipMemsetAsync(gsums, 0, 2 * EMB * 4, stream);
    stats_kernel<<<512, 256, 0, stream>>>(tmp, gsums, N);
    float* outp = (l == L - 1) ? (float*)d_out : h;
    bn_kernel<<<(N * (EMB / 4) + 255) / 256, 256, 0, stream>>>(
        tmp, gsums, gamma + (size_t)l * EMB, beta + (size_t)l * EMB,
        outp, N, (l < L - 1) ? 1 : 0);
  }
}

// Round 8
// 832.254 us; speedup vs baseline: 1.4237x; 1.2896x over previous
//
#include <hip/hip_runtime.h>

#define EMB 64
#define HID 128
#define BONDF 16
#define ATOMF 32

typedef __attribute__((ext_vector_type(8))) short short8v;   // 8 bf16 (4 VGPRs)
typedef __attribute__((ext_vector_type(16))) float f32x16;   // MFMA 32x32 accum

__device__ __forceinline__ unsigned short f32_to_bf16_rne(float f) {
  unsigned u = __float_as_uint(f);
  u = (u + 0x7FFFu + ((u >> 16) & 1u)) >> 16;
  return (unsigned short)u;
}

// ---------------- embedding: h = x @ Wemb.T (fp32) ----------------
__global__ __launch_bounds__(256) void embed_kernel(
    const float* __restrict__ x, const float* __restrict__ Wemb,
    float* __restrict__ h, int N)
{
  __shared__ float sW[EMB * ATOMF];
  int tid = threadIdx.x;
  for (int i = tid; i < EMB * ATOMF; i += 256) sW[i] = Wemb[i];
  __syncthreads();
  int row = blockIdx.x * 256 + tid;
  if (row >= N) return;
  float xin[ATOMF];
  const float4* xr = reinterpret_cast<const float4*>(x + (size_t)row * ATOMF);
#pragma unroll
  for (int k4 = 0; k4 < ATOMF / 4; ++k4) {
    float4 v = xr[k4];
    xin[4 * k4 + 0] = v.x; xin[4 * k4 + 1] = v.y;
    xin[4 * k4 + 2] = v.z; xin[4 * k4 + 3] = v.w;
  }
  float4* hr = reinterpret_cast<float4*>(h + (size_t)row * EMB);
  for (int o4 = 0; o4 < EMB / 4; ++o4) {
    float acc[4];
#pragma unroll
    for (int c = 0; c < 4; ++c) {
      const float* wrow = sW + (o4 * 4 + c) * ATOMF;
      float a = 0.f;
#pragma unroll
      for (int kk = 0; kk < ATOMF / 4; ++kk) {
        float4 w = reinterpret_cast<const float4*>(wrow)[kk];
        a = fmaf(w.x, xin[4 * kk + 0], a);
        a = fmaf(w.y, xin[4 * kk + 1], a);
        a = fmaf(w.z, xin[4 * kk + 2], a);
        a = fmaf(w.w, xin[4 * kk + 3], a);
      }
      acc[c] = a;
    }
    hr[o4] = make_float4(acc[0], acc[1], acc[2], acc[3]);
  }
}

// ------------- fp32 -> bf16 weight conversion (once/call) -------------
__global__ __launch_bounds__(256) void cvt_bf16_kernel(
    const float* __restrict__ s, unsigned short* __restrict__ d, int n)
{
  int i = blockIdx.x * 256 + threadIdx.x;
  if (i < n) d[i] = f32_to_bf16_rne(s[i]);
}

// ------------- degree histogram -------------
__global__ __launch_bounds__(256) void deg_kernel(
    const int* __restrict__ ei, int* __restrict__ deg, int E)
{
  int e = blockIdx.x * 256 + threadIdx.x;
  if (e < E) atomicAdd(&deg[ei[E + e]], 1);
}

// ------------- hierarchical scan -------------
__global__ __launch_bounds__(256) void scan1_kernel(
    const int* __restrict__ deg, int* __restrict__ off,
    int* __restrict__ bsum, int n)
{
  __shared__ int ws[4];
  int tid = threadIdx.x, lane = tid & 63, wid = tid >> 6;
  int i = blockIdx.x * 256 + tid;
  int v = (i < n) ? deg[i] : 0;
  int x = v;
#pragma unroll
  for (int d = 1; d < 64; d <<= 1) {
    int t = __shfl_up(x, d, 64);
    if (lane >= d) x += t;
  }
  if (lane == 63) ws[wid] = x;
  __syncthreads();
  int add = 0;
  for (int w = 0; w < wid; ++w) add += ws[w];
  if (i < n) off[i] = x + add - v;
  if (tid == 255) bsum[blockIdx.x] = x + add;
}

__global__ __launch_bounds__(256) void scan_small_kernel(
    const int* __restrict__ deg, int* __restrict__ off, int n)
{
  __shared__ int warpsums[4];
  __shared__ int s_carry;
  int tid = threadIdx.x, lane = tid & 63, wid = tid >> 6;
  if (tid == 0) s_carry = 0;
  __syncthreads();
  for (int base = 0; base < n; base += 256) {
    int i = base + tid;
    int v = (i < n) ? deg[i] : 0;
    int x = v;
#pragma unroll
    for (int d = 1; d < 64; d <<= 1) {
      int t = __shfl_up(x, d, 64);
      if (lane >= d) x += t;
    }
    if (lane == 63) warpsums[wid] = x;
    __syncthreads();
    int wsum = 0;
    for (int w = 0; w < wid; ++w) wsum += warpsums[w];
    int incl = x + wsum + s_carry;
    if (i < n) off[i] = incl - v;
    __syncthreads();
    if (tid == 255) s_carry = incl;
    __syncthreads();
  }
  if (tid == 0) off[n] = s_carry;
}

__global__ __launch_bounds__(256) void scan3_kernel(
    int* __restrict__ off, const int* __restrict__ boff, int n)
{
  int i = blockIdx.x * 256 + threadIdx.x;
  if (i < n) off[i] += boff[blockIdx.x];
  if (i == 0) off[n] = boff[gridDim.x];
}

// ------------- place edges into CSR slots -------------
__global__ __launch_bounds__(256) void place_kernel(
    const int* __restrict__ ei, const int* __restrict__ off,
    int* __restrict__ cursor, int* __restrict__ csr_src,
    int* __restrict__ csr_eid, int E)
{
  int e = blockIdx.x * 256 + threadIdx.x;
  if (e >= E) return;
  int d = ei[E + e];
  int pos = atomicAdd(&cursor[d], 1);
  int slot = off[d] + pos;
  csr_src[slot] = ei[e];
  csr_eid[slot] = e;
}

// ------------- S_ea[i] = sum_{e->i} edge_attr[e] -------------
__global__ __launch_bounds__(256) void gather_ea_kernel(
    const float* __restrict__ ea, const int* __restrict__ off,
    const int* __restrict__ csr_eid, float* __restrict__ S_ea, int N)
{
  int f = threadIdx.x & 15;
  int node = blockIdx.x * 16 + (threadIdx.x >> 4);
  if (node >= N) return;
  float acc = 0.f;
  int s0 = off[node], s1 = off[node + 1];
  for (int e = s0; e < s1; ++e)
    acc += ea[(size_t)csr_eid[e] * BONDF + f];
  S_ea[(size_t)node * BONDF + f] = acc;
}

// ------------- aggregate + edge-emb term, emit bf16 -------------
// aggr16[i][k] = bf16( h[i][k] + sum_{e->i} h[src[e]][k]
//                     + dot(We[k][:], S_ea[i][:]) + (deg+1)*be[k] )
__global__ __launch_bounds__(256) void aggregate_ea_kernel(
    const float* __restrict__ h, const int* __restrict__ off,
    const int* __restrict__ csr_src, const float* __restrict__ S_ea,
    const float* __restrict__ We_l, const float* __restrict__ be_l,
    unsigned short* __restrict__ aggr16, int N)
{
  __shared__ float sWet[BONDF * EMB];  // transposed: [f][k], conflict-free reads
  __shared__ float sbe[EMB];
  int tid = threadIdx.x;
  for (int i = tid; i < EMB * BONDF; i += 256) {
    int k = i >> 4, f = i & 15;
    sWet[f * EMB + k] = We_l[i];
  }
  if (tid < EMB) sbe[tid] = be_l[tid];
  __syncthreads();
  int lane = tid & 63;
  int node = blockIdx.x * 4 + (tid >> 6);
  if (node >= N) return;
  float acc = h[(size_t)node * EMB + lane];  // self loop
  int s0 = off[node], s1 = off[node + 1];
  int e = s0;
  for (; e + 1 < s1; e += 2) {
    int a = csr_src[e], b = csr_src[e + 1];
    float va = h[(size_t)a * EMB + lane];
    float vb = h[(size_t)b * EMB + lane];
    acc += va;
    acc += vb;
  }
  if (e < s1) acc += h[(size_t)csr_src[e] * EMB + lane];
  float dp1 = (float)(s1 - s0) + 1.0f;
  acc = fmaf(sbe[lane], dp1, acc);
  const float* sea = S_ea + (size_t)node * BONDF;
#pragma unroll
  for (int f = 0; f < BONDF; ++f)
    acc = fmaf(sWet[f * EMB + lane], sea[f], acc);
  aggr16[(size_t)node * EMB + lane] = f32_to_bf16_rne(acc);
}

// ------------- MFMA MLP: tmp[32-row chunk] = W2·relu(W1·in^T + b1) (^T) -------------
// Swapped-operand form; hidden stays in registers (cvt_pk + shfl_xor(32)), no LDS.
__global__ __launch_bounds__(256) void mlp_mfma_kernel(
    const unsigned short* __restrict__ aggr16,  // [N][64] bf16
    const unsigned short* __restrict__ W1b,     // [128][64] bf16
    const unsigned short* __restrict__ W2b,     // [64][128] bf16
    const float* __restrict__ b1,               // [128]
    float* __restrict__ tmp, int N)
{
  int wid = threadIdx.x >> 6;
  int lane = threadIdx.x & 63;
  int chunk = blockIdx.x * 4 + wid;
  int row0 = chunk * 32;
  if (row0 >= N) return;
  int col = lane & 31;   // data-row within chunk; also W-row within M-tile
  int g = lane >> 5;     // k-half selector
  int row = row0 + col;
  int rowc = min(row, N - 1);

  // ---- GEMM1: C1^T[128 hid][32 rows] = W1[128x64] · in^T ----
  f32x16 acc1[4] = {};
#pragma unroll
  for (int kt = 0; kt < 4; ++kt) {
    short8v bfrag = *reinterpret_cast<const short8v*>(
        aggr16 + (size_t)rowc * EMB + kt * 16 + g * 8);
#pragma unroll
    for (int mt = 0; mt < 4; ++mt) {
      short8v afrag = *reinterpret_cast<const short8v*>(
          W1b + (size_t)(mt * 32 + col) * EMB + kt * 16 + g * 8);
      acc1[mt] = __builtin_amdgcn_mfma_f32_32x32x16_bf16(afrag, bfrag, acc1[mt], 0, 0, 0);
    }
  }

  // ---- +b1, relu, pack to bf16 pairs: u[2t],u[2t+1] from acc1[t>>2][4(t&3)..+3] ----
  unsigned u[32];
#pragma unroll
  for (int t = 0; t < 16; ++t) {
    const int mt = t >> 2, q = t & 3;
    float v0 = fmaxf(acc1[mt][4 * q + 0] + b1[mt * 32 + 8 * q + 4 * g + 0], 0.f);
    float v1 = fmaxf(acc1[mt][4 * q + 1] + b1[mt * 32 + 8 * q + 4 * g + 1], 0.f);
    float v2 = fmaxf(acc1[mt][4 * q + 2] + b1[mt * 32 + 8 * q + 4 * g + 2], 0.f);
    float v3 = fmaxf(acc1[mt][4 * q + 3] + b1[mt * 32 + 8 * q + 4 * g + 3], 0.f);
    asm("v_cvt_pk_bf16_f32 %0, %1, %2" : "=v"(u[2 * t + 0]) : "v"(v0), "v"(v1));
    asm("v_cvt_pk_bf16_f32 %0, %1, %2" : "=v"(u[2 * t + 1]) : "v"(v2), "v"(v3));
  }

  // ---- build B2 fragments: B2[k][n] = H[n][k] = C1^T ----
  // frag(kt2): g=0 -> [e0,e1, pe0,pe1]; g=1 -> [po0,po1, o0,o1]
  short8v b2f[8];
#pragma unroll
  for (int kt2 = 0; kt2 < 8; ++kt2) {
    unsigned e0 = u[4 * kt2 + 0], e1 = u[4 * kt2 + 1];
    unsigned o0 = u[4 * kt2 + 2], o1 = u[4 * kt2 + 3];
    unsigned pe0 = (unsigned)__shfl_xor((int)e0, 32, 64);
    unsigned pe1 = (unsigned)__shfl_xor((int)e1, 32, 64);
    unsigned po0 = (unsigned)__shfl_xor((int)o0, 32, 64);
    unsigned po1 = (unsigned)__shfl_xor((int)o1, 32, 64);
    union { unsigned w[4]; short8v v; } cvt;
    cvt.w[0] = (g == 0) ? e0 : po0;
    cvt.w[1] = (g == 0) ? e1 : po1;
    cvt.w[2] = (g == 0) ? pe0 : o0;
    cvt.w[3] = (g == 0) ? pe1 : o1;
    b2f[kt2] = cvt.v;
  }

  // ---- GEMM2: C2^T[64 out][32 rows] = W2[64x128] · H^T ----
  f32x16 acc2[2] = {};
#pragma unroll
  for (int kt2 = 0; kt2 < 8; ++kt2) {
#pragma unroll
    for (int mt2 = 0; mt2 < 2; ++mt2) {
      short8v a2 = *reinterpret_cast<const short8v*>(
          W2b + (size_t)(mt2 * 32 + col) * HID + kt2 * 16 + g * 8);
      acc2[mt2] = __builtin_amdgcn_mfma_f32_32x32x16_bf16(a2, b2f[kt2], acc2[mt2], 0, 0, 0);
    }
  }

  // ---- store (b2 omitted: cancels in BatchNorm) ----
  if (row < N) {
#pragma unroll
    for (int mt2 = 0; mt2 < 2; ++mt2)
#pragma unroll
      for (int r = 0; r < 16; ++r) {
        int o = mt2 * 32 + (r & 3) + 8 * (r >> 2) + 4 * g;
        tmp[(size_t)row * EMB + o] = acc2[mt2][r];
      }
  }
}

// ------------- per-layer column stats (sum, sumsq) -------------
__global__ __launch_bounds__(256) void stats_kernel(
    const float* __restrict__ tmp, float* __restrict__ gsums, int N)
{
  __shared__ float sh[256], sh2[256];
  int tid = threadIdx.x;
  int c = tid & 63, rg = tid >> 6;
  float s = 0.f, s2 = 0.f;
  for (int r = blockIdx.x * 4 + rg; r < N; r += gridDim.x * 4) {
    float v = tmp[(size_t)r * EMB + c];
    s += v; s2 += v * v;
  }
  sh[tid] = s; sh2[tid] = s2;
  __syncthreads();
  if (tid < 64) {
    s = sh[tid] + sh[tid + 64] + sh[tid + 128] + sh[tid + 192];
    s2 = sh2[tid] + sh2[tid + 64] + sh2[tid + 128] + sh2[tid + 192];
    atomicAdd(&gsums[c], s);
    atomicAdd(&gsums[EMB + c], s2);
  }
}

// ------------- per-layer BN + (mish) -------------
__global__ __launch_bounds__(256) void bn_kernel(
    const float* __restrict__ tmp, const float* __restrict__ gsums,
    const float* __restrict__ gamma, const float* __restrict__ beta,
    float* __restrict__ out, int N, int apply_mish)
{
  int idx = blockIdx.x * 256 + threadIdx.x;
  int total = N * (EMB / 4);
  if (idx >= total) return;
  int c4 = idx & (EMB / 4 - 1);
  float invN = 1.0f / (float)N;
  float4 v = reinterpret_cast<const float4*>(tmp)[idx];
  float o[4] = {v.x, v.y, v.z, v.w};
#pragma unroll
  for (int c = 0; c < 4; ++c) {
    int col = c4 * 4 + c;
    float mu = gsums[col] * invN;
    float var = gsums[EMB + col] * invN - mu * mu;
    float sc = gamma[col] * rsqrtf(var + 1e-5f);
    float shf = beta[col] - mu * sc;
    float y = o[c] * sc + shf;
    if (apply_mish) {
      float sp = (y > 20.f) ? y : log1pf(expf(y));
      y = y * tanhf(sp);
    }
    o[c] = y;
  }
  reinterpret_cast<float4*>(out)[idx] = make_float4(o[0], o[1], o[2], o[3]);
}

extern "C" void kernel_launch(void* const* d_in, const int* in_sizes, int n_in,
                              void* d_out, int out_size, void* d_ws, size_t ws_size,
                              hipStream_t stream) {
  (void)n_in; (void)out_size; (void)ws_size;
  const float* x     = (const float*)d_in[0];
  const float* ea    = (const float*)d_in[1];
  const float* Wemb  = (const float*)d_in[2];
  const float* W1    = (const float*)d_in[3];
  const float* b1    = (const float*)d_in[4];
  // d_in[5] = W2 ; d_in[6] = b2 (cancels under BN, unused)
  const float* W2    = (const float*)d_in[5];
  const float* We    = (const float*)d_in[7];
  const float* be    = (const float*)d_in[8];
  const float* gamma = (const float*)d_in[9];
  const float* beta  = (const float*)d_in[10];
  const int*   ei    = (const int*)d_in[11];

  int N = in_sizes[0] / ATOMF;
  int E = in_sizes[11] / 2;
  int L = in_sizes[3] / (HID * EMB);

  char* w = (char*)d_ws;
  auto alloc = [&](size_t bytes) {
    void* p = (void*)w;
    w += (bytes + 255) & ~(size_t)255;
    return p;
  };
  float*          h      = (float*)alloc((size_t)N * EMB * 4);
  float*          tmp    = (float*)alloc((size_t)N * EMB * 4);
  unsigned short* aggr16 = (unsigned short*)alloc((size_t)N * EMB * 2);
  float*          S_ea   = (float*)alloc((size_t)N * BONDF * 4);
  int*            deg    = (int*)alloc((size_t)N * 4);
  int*            off    = (int*)alloc((size_t)(N + 1) * 4);
  int*            cursor = (int*)alloc((size_t)N * 4);
  int*            csr    = (int*)alloc((size_t)E * 4);
  int*            csre   = (int*)alloc((size_t)E * 4);
  int*            bsum   = (int*)alloc(1024 * 4);
  int*            boff   = (int*)alloc(1025 * 4);
  float*          gsums  = (float*)alloc(2 * EMB * 4);
  unsigned short* W1b    = (unsigned short*)alloc((size_t)L * HID * EMB * 2);
  unsigned short* W2b    = (unsigned short*)alloc((size_t)L * HID * EMB * 2);

  hipMemsetAsync(deg, 0, (size_t)N * 4, stream);
  hipMemsetAsync(cursor, 0, (size_t)N * 4, stream);

  int nW = L * HID * EMB;
  cvt_bf16_kernel<<<(nW + 255) / 256, 256, 0, stream>>>(W1, W1b, nW);
  cvt_bf16_kernel<<<(nW + 255) / 256, 256, 0, stream>>>(W2, W2b, nW);

  int nb = (N + 255) / 256;
  deg_kernel<<<(E + 255) / 256, 256, 0, stream>>>(ei, deg, E);
  scan1_kernel<<<nb, 256, 0, stream>>>(deg, off, bsum, N);
  scan_small_kernel<<<1, 256, 0, stream>>>(bsum, boff, nb);
  scan3_kernel<<<nb, 256, 0, stream>>>(off, boff, N);
  place_kernel<<<(E + 255) / 256, 256, 0, stream>>>(ei, off, cursor, csr, csre, E);
  gather_ea_kernel<<<(N + 15) / 16, 256, 0, stream>>>(ea, off, csre, S_ea, N);
  embed_kernel<<<(N + 255) / 256, 256, 0, stream>>>(x, Wemb, h, N);

  int nchunk = (N + 31) / 32;
  for (int l = 0; l < L; ++l) {
    aggregate_ea_kernel<<<(N + 3) / 4, 256, 0, stream>>>(
        h, off, csr, S_ea, We + (size_t)l * EMB * BONDF, be + (size_t)l * EMB,
        aggr16, N);
    mlp_mfma_kernel<<<(nchunk + 3) / 4, 256, 0, stream>>>(
        aggr16, W1b + (size_t)l * HID * EMB, W2b + (size_t)l * HID * EMB,
        b1 + (size_t)l * HID, tmp, N);
    hipMemsetAsync(gsums, 0, 2 * EMB * 4, stream);
    stats_kernel<<<512, 256, 0, stream>>>(tmp, gsums, N);
    float* outp = (l == L - 1) ? (float*)d_out : h;
    bn_kernel<<<(N * (EMB / 4) + 255) / 256, 256, 0, stream>>>(
        tmp, gsums, gamma + (size_t)l * EMB, beta + (size_t)l * EMB,
        outp, N, (l < L - 1) ? 1 : 0);
  }
}

// Round 9
// 770.922 us; speedup vs baseline: 1.5370x; 1.0796x over previous
//
#include <hip/hip_runtime.h>

#define EMB 64
#define HID 128
#define BONDF 16
#define ATOMF 32

typedef __attribute__((ext_vector_type(8))) short short8v;   // 8 bf16 (4 VGPRs)
typedef __attribute__((ext_vector_type(16))) float f32x16;   // MFMA 32x32 accum

__device__ __forceinline__ unsigned short f32_to_bf16_rne(float f) {
  unsigned u = __float_as_uint(f);
  u = (u + 0x7FFFu + ((u >> 16) & 1u)) >> 16;
  return (unsigned short)u;
}

// ---------------- embedding: h = x @ Wemb.T (fp32) ----------------
__global__ __launch_bounds__(256) void embed_kernel(
    const float* __restrict__ x, const float* __restrict__ Wemb,
    float* __restrict__ h, int N)
{
  __shared__ float sW[EMB * ATOMF];
  int tid = threadIdx.x;
  for (int i = tid; i < EMB * ATOMF; i += 256) sW[i] = Wemb[i];
  __syncthreads();
  int row = blockIdx.x * 256 + tid;
  if (row >= N) return;
  float xin[ATOMF];
  const float4* xr = reinterpret_cast<const float4*>(x + (size_t)row * ATOMF);
#pragma unroll
  for (int k4 = 0; k4 < ATOMF / 4; ++k4) {
    float4 v = xr[k4];
    xin[4 * k4 + 0] = v.x; xin[4 * k4 + 1] = v.y;
    xin[4 * k4 + 2] = v.z; xin[4 * k4 + 3] = v.w;
  }
  float4* hr = reinterpret_cast<float4*>(h + (size_t)row * EMB);
  for (int o4 = 0; o4 < EMB / 4; ++o4) {
    float acc[4];
#pragma unroll
    for (int c = 0; c < 4; ++c) {
      const float* wrow = sW + (o4 * 4 + c) * ATOMF;
      float a = 0.f;
#pragma unroll
      for (int kk = 0; kk < ATOMF / 4; ++kk) {
        float4 w = reinterpret_cast<const float4*>(wrow)[kk];
        a = fmaf(w.x, xin[4 * kk + 0], a);
        a = fmaf(w.y, xin[4 * kk + 1], a);
        a = fmaf(w.z, xin[4 * kk + 2], a);
        a = fmaf(w.w, xin[4 * kk + 3], a);
      }
      acc[c] = a;
    }
    hr[o4] = make_float4(acc[0], acc[1], acc[2], acc[3]);
  }
}

// ------------- fp32 -> bf16 weight conversion (once/call) -------------
__global__ __launch_bounds__(256) void cvt_bf16_kernel(
    const float* __restrict__ s, unsigned short* __restrict__ d, int n)
{
  int i = blockIdx.x * 256 + threadIdx.x;
  if (i < n) d[i] = f32_to_bf16_rne(s[i]);
}

// ------------- degree histogram -------------
__global__ __launch_bounds__(256) void deg_kernel(
    const int* __restrict__ ei, int* __restrict__ deg, int E)
{
  int e = blockIdx.x * 256 + threadIdx.x;
  if (e < E) atomicAdd(&deg[ei[E + e]], 1);
}

// ------------- hierarchical scan -------------
__global__ __launch_bounds__(256) void scan1_kernel(
    const int* __restrict__ deg, int* __restrict__ off,
    int* __restrict__ bsum, int n)
{
  __shared__ int ws[4];
  int tid = threadIdx.x, lane = tid & 63, wid = tid >> 6;
  int i = blockIdx.x * 256 + tid;
  int v = (i < n) ? deg[i] : 0;
  int x = v;
#pragma unroll
  for (int d = 1; d < 64; d <<= 1) {
    int t = __shfl_up(x, d, 64);
    if (lane >= d) x += t;
  }
  if (lane == 63) ws[wid] = x;
  __syncthreads();
  int add = 0;
  for (int w = 0; w < wid; ++w) add += ws[w];
  if (i < n) off[i] = x + add - v;
  if (tid == 255) bsum[blockIdx.x] = x + add;
}

__global__ __launch_bounds__(256) void scan_small_kernel(
    const int* __restrict__ deg, int* __restrict__ off, int n)
{
  __shared__ int warpsums[4];
  __shared__ int s_carry;
  int tid = threadIdx.x, lane = tid & 63, wid = tid >> 6;
  if (tid == 0) s_carry = 0;
  __syncthreads();
  for (int base = 0; base < n; base += 256) {
    int i = base + tid;
    int v = (i < n) ? deg[i] : 0;
    int x = v;
#pragma unroll
    for (int d = 1; d < 64; d <<= 1) {
      int t = __shfl_up(x, d, 64);
      if (lane >= d) x += t;
    }
    if (lane == 63) warpsums[wid] = x;
    __syncthreads();
    int wsum = 0;
    for (int w = 0; w < wid; ++w) wsum += warpsums[w];
    int incl = x + wsum + s_carry;
    if (i < n) off[i] = incl - v;
    __syncthreads();
    if (tid == 255) s_carry = incl;
    __syncthreads();
  }
  if (tid == 0) off[n] = s_carry;
}

__global__ __launch_bounds__(256) void scan3_kernel(
    int* __restrict__ off, const int* __restrict__ boff, int n)
{
  int i = blockIdx.x * 256 + threadIdx.x;
  if (i < n) off[i] += boff[blockIdx.x];
  if (i == 0) off[n] = boff[gridDim.x];
}

// ------------- place edges into CSR slots -------------
__global__ __launch_bounds__(256) void place_kernel(
    const int* __restrict__ ei, const int* __restrict__ off,
    int* __restrict__ cursor, int* __restrict__ csr_src,
    int* __restrict__ csr_eid, int E)
{
  int e = blockIdx.x * 256 + threadIdx.x;
  if (e >= E) return;
  int d = ei[E + e];
  int pos = atomicAdd(&cursor[d], 1);
  int slot = off[d] + pos;
  csr_src[slot] = ei[e];
  csr_eid[slot] = e;
}

// ------------- S_ea[i] = sum_{e->i} edge_attr[e] -------------
__global__ __launch_bounds__(256) void gather_ea_kernel(
    const float* __restrict__ ea, const int* __restrict__ off,
    const int* __restrict__ csr_eid, float* __restrict__ S_ea, int N)
{
  int f = threadIdx.x & 15;
  int node = blockIdx.x * 16 + (threadIdx.x >> 4);
  if (node >= N) return;
  float acc = 0.f;
  int s0 = off[node], s1 = off[node + 1];
  for (int e = s0; e < s1; ++e)
    acc += ea[(size_t)csr_eid[e] * BONDF + f];
  S_ea[(size_t)node * BONDF + f] = acc;
}

// ------------- aggregate + edge-emb term, emit bf16 -------------
// Latency-optimized: int4 index broadcast + 4 row-loads in flight.
__global__ __launch_bounds__(256) void aggregate_ea_kernel(
    const float* __restrict__ h, const int* __restrict__ off,
    const int* __restrict__ csr_src, const float* __restrict__ S_ea,
    const float* __restrict__ We_l, const float* __restrict__ be_l,
    unsigned short* __restrict__ aggr16, int N)
{
  __shared__ float sWet[BONDF * EMB];  // transposed: [f][k]
  __shared__ float sbe[EMB];
  int tid = threadIdx.x;
  for (int i = tid; i < EMB * BONDF; i += 256) {
    int k = i >> 4, f = i & 15;
    sWet[f * EMB + k] = We_l[i];
  }
  if (tid < EMB) sbe[tid] = be_l[tid];
  __syncthreads();
  int lane = tid & 63;
  int node = blockIdx.x * 4 + (tid >> 6);
  if (node >= N) return;
  float acc = h[(size_t)node * EMB + lane];  // self loop
  int s0 = off[node], s1 = off[node + 1];
  int e = s0;
  // peel to 16B-aligned csr_src index
  for (; e < s1 && (e & 3); ++e)
    acc += h[(size_t)csr_src[e] * EMB + lane];
  // 4 independent row loads in flight per iteration; index load is one
  // 16B broadcast and affine in e (hoistable by the scheduler)
  for (; e + 3 < s1; e += 4) {
    int4 idx = *reinterpret_cast<const int4*>(csr_src + e);
    float v0 = h[(size_t)idx.x * EMB + lane];
    float v1 = h[(size_t)idx.y * EMB + lane];
    float v2 = h[(size_t)idx.z * EMB + lane];
    float v3 = h[(size_t)idx.w * EMB + lane];
    acc += v0; acc += v1; acc += v2; acc += v3;
  }
  for (; e < s1; ++e)
    acc += h[(size_t)csr_src[e] * EMB + lane];
  float dp1 = (float)(s1 - s0) + 1.0f;
  acc = fmaf(sbe[lane], dp1, acc);
  const float* sea = S_ea + (size_t)node * BONDF;
#pragma unroll
  for (int f = 0; f < BONDF; ++f)
    acc = fmaf(sWet[f * EMB + lane], sea[f], acc);
  aggr16[(size_t)node * EMB + lane] = f32_to_bf16_rne(acc);
}

// ------------- MFMA MLP: tmp[32-row chunk] = W2·relu(W1·in^T + b1) (^T) -------------
__global__ __launch_bounds__(256) void mlp_mfma_kernel(
    const unsigned short* __restrict__ aggr16,  // [N][64] bf16
    const unsigned short* __restrict__ W1b,     // [128][64] bf16
    const unsigned short* __restrict__ W2b,     // [64][128] bf16
    const float* __restrict__ b1,               // [128]
    float* __restrict__ tmp, int N)
{
  int wid = threadIdx.x >> 6;
  int lane = threadIdx.x & 63;
  int chunk = blockIdx.x * 4 + wid;
  int row0 = chunk * 32;
  if (row0 >= N) return;
  int col = lane & 31;
  int g = lane >> 5;
  int row = row0 + col;
  int rowc = min(row, N - 1);

  f32x16 acc1[4] = {};
#pragma unroll
  for (int kt = 0; kt < 4; ++kt) {
    short8v bfrag = *reinterpret_cast<const short8v*>(
        aggr16 + (size_t)rowc * EMB + kt * 16 + g * 8);
#pragma unroll
    for (int mt = 0; mt < 4; ++mt) {
      short8v afrag = *reinterpret_cast<const short8v*>(
          W1b + (size_t)(mt * 32 + col) * EMB + kt * 16 + g * 8);
      acc1[mt] = __builtin_amdgcn_mfma_f32_32x32x16_bf16(afrag, bfrag, acc1[mt], 0, 0, 0);
    }
  }

  unsigned u[32];
#pragma unroll
  for (int t = 0; t < 16; ++t) {
    const int mt = t >> 2, q = t & 3;
    float v0 = fmaxf(acc1[mt][4 * q + 0] + b1[mt * 32 + 8 * q + 4 * g + 0], 0.f);
    float v1 = fmaxf(acc1[mt][4 * q + 1] + b1[mt * 32 + 8 * q + 4 * g + 1], 0.f);
    float v2 = fmaxf(acc1[mt][4 * q + 2] + b1[mt * 32 + 8 * q + 4 * g + 2], 0.f);
    float v3 = fmaxf(acc1[mt][4 * q + 3] + b1[mt * 32 + 8 * q + 4 * g + 3], 0.f);
    asm("v_cvt_pk_bf16_f32 %0, %1, %2" : "=v"(u[2 * t + 0]) : "v"(v0), "v"(v1));
    asm("v_cvt_pk_bf16_f32 %0, %1, %2" : "=v"(u[2 * t + 1]) : "v"(v2), "v"(v3));
  }

  short8v b2f[8];
#pragma unroll
  for (int kt2 = 0; kt2 < 8; ++kt2) {
    unsigned e0 = u[4 * kt2 + 0], e1 = u[4 * kt2 + 1];
    unsigned o0 = u[4 * kt2 + 2], o1 = u[4 * kt2 + 3];
    unsigned pe0 = (unsigned)__shfl_xor((int)e0, 32, 64);
    unsigned pe1 = (unsigned)__shfl_xor((int)e1, 32, 64);
    unsigned po0 = (unsigned)__shfl_xor((int)o0, 32, 64);
    unsigned po1 = (unsigned)__shfl_xor((int)o1, 32, 64);
    union { unsigned w[4]; short8v v; } cvt;
    cvt.w[0] = (g == 0) ? e0 : po0;
    cvt.w[1] = (g == 0) ? e1 : po1;
    cvt.w[2] = (g == 0) ? pe0 : o0;
    cvt.w[3] = (g == 0) ? pe1 : o1;
    b2f[kt2] = cvt.v;
  }

  f32x16 acc2[2] = {};
#pragma unroll
  for (int kt2 = 0; kt2 < 8; ++kt2) {
#pragma unroll
    for (int mt2 = 0; mt2 < 2; ++mt2) {
      short8v a2 = *reinterpret_cast<const short8v*>(
          W2b + (size_t)(mt2 * 32 + col) * HID + kt2 * 16 + g * 8);
      acc2[mt2] = __builtin_amdgcn_mfma_f32_32x32x16_bf16(a2, b2f[kt2], acc2[mt2], 0, 0, 0);
    }
  }

  if (row < N) {
#pragma unroll
    for (int mt2 = 0; mt2 < 2; ++mt2)
#pragma unroll
      for (int r = 0; r < 16; ++r) {
        int o = mt2 * 32 + (r & 3) + 8 * (r >> 2) + 4 * g;
        tmp[(size_t)row * EMB + o] = acc2[mt2][r];
      }
  }
}

// ------------- per-layer column stats (sum, sumsq) -------------
__global__ __launch_bounds__(256) void stats_kernel(
    const float* __restrict__ tmp, float* __restrict__ gsums, int N)
{
  __shared__ float sh[256], sh2[256];
  int tid = threadIdx.x;
  int c = tid & 63, rg = tid >> 6;
  float s = 0.f, s2 = 0.f;
  for (int r = blockIdx.x * 4 + rg; r < N; r += gridDim.x * 4) {
    float v = tmp[(size_t)r * EMB + c];
    s += v; s2 += v * v;
  }
  sh[tid] = s; sh2[tid] = s2;
  __syncthreads();
  if (tid < 64) {
    s = sh[tid] + sh[tid + 64] + sh[tid + 128] + sh[tid + 192];
    s2 = sh2[tid] + sh2[tid + 64] + sh2[tid + 128] + sh2[tid + 192];
    atomicAdd(&gsums[c], s);
    atomicAdd(&gsums[EMB + c], s2);
  }
}

// ------------- per-layer BN + (mish) -------------
__global__ __launch_bounds__(256) void bn_kernel(
    const float* __restrict__ tmp, const float* __restrict__ gsums,
    const float* __restrict__ gamma, const float* __restrict__ beta,
    float* __restrict__ out, int N, int apply_mish)
{
  int idx = blockIdx.x * 256 + threadIdx.x;
  int total = N * (EMB / 4);
  if (idx >= total) return;
  int c4 = idx & (EMB / 4 - 1);
  float invN = 1.0f / (float)N;
  float4 v = reinterpret_cast<const float4*>(tmp)[idx];
  float o[4] = {v.x, v.y, v.z, v.w};
#pragma unroll
  for (int c = 0; c < 4; ++c) {
    int col = c4 * 4 + c;
    float mu = gsums[col] * invN;
    float var = gsums[EMB + col] * invN - mu * mu;
    float sc = gamma[col] * rsqrtf(var + 1e-5f);
    float shf = beta[col] - mu * sc;
    float y = o[c] * sc + shf;
    if (apply_mish) {
      float sp = (y > 20.f) ? y : log1pf(expf(y));
      y = y * tanhf(sp);
    }
    o[c] = y;
  }
  reinterpret_cast<float4*>(out)[idx] = make_float4(o[0], o[1], o[2], o[3]);
}

extern "C" void kernel_launch(void* const* d_in, const int* in_sizes, int n_in,
                              void* d_out, int out_size, void* d_ws, size_t ws_size,
                              hipStream_t stream) {
  (void)n_in; (void)out_size; (void)ws_size;
  const float* x     = (const float*)d_in[0];
  const float* ea    = (const float*)d_in[1];
  const float* Wemb  = (const float*)d_in[2];
  const float* W1    = (const float*)d_in[3];
  const float* b1    = (const float*)d_in[4];
  const float* W2    = (const float*)d_in[5];
  const float* We    = (const float*)d_in[7];
  const float* be    = (const float*)d_in[8];
  const float* gamma = (const float*)d_in[9];
  const float* beta  = (const float*)d_in[10];
  const int*   ei    = (const int*)d_in[11];

  int N = in_sizes[0] / ATOMF;
  int E = in_sizes[11] / 2;
  int L = in_sizes[3] / (HID * EMB);

  char* w = (char*)d_ws;
  auto alloc = [&](size_t bytes) {
    void* p = (void*)w;
    w += (bytes + 255) & ~(size_t)255;
    return p;
  };
  float*          h      = (float*)alloc((size_t)N * EMB * 4);
  float*          tmp    = (float*)alloc((size_t)N * EMB * 4);
  unsigned short* aggr16 = (unsigned short*)alloc((size_t)N * EMB * 2);
  float*          S_ea   = (float*)alloc((size_t)N * BONDF * 4);
  int*            deg    = (int*)alloc((size_t)N * 4);
  int*            off    = (int*)alloc((size_t)(N + 1) * 4);
  int*            cursor = (int*)alloc((size_t)N * 4);
  int*            csr    = (int*)alloc((size_t)E * 4);
  int*            csre   = (int*)alloc((size_t)E * 4);
  int*            bsum   = (int*)alloc(1024 * 4);
  int*            boff   = (int*)alloc(1025 * 4);
  float*          gsums  = (float*)alloc(2 * EMB * 4);
  unsigned short* W1b    = (unsigned short*)alloc((size_t)L * HID * EMB * 2);
  unsigned short* W2b    = (unsigned short*)alloc((size_t)L * HID * EMB * 2);

  hipMemsetAsync(deg, 0, (size_t)N * 4, stream);
  hipMemsetAsync(cursor, 0, (size_t)N * 4, stream);

  int nW = L * HID * EMB;
  cvt_bf16_kernel<<<(nW + 255) / 256, 256, 0, stream>>>(W1, W1b, nW);
  cvt_bf16_kernel<<<(nW + 255) / 256, 256, 0, stream>>>(W2, W2b, nW);

  int nb = (N + 255) / 256;
  deg_kernel<<<(E + 255) / 256, 256, 0, stream>>>(ei, deg, E);
  scan1_kernel<<<nb, 256, 0, stream>>>(deg, off, bsum, N);
  scan_small_kernel<<<1, 256, 0, stream>>>(bsum, boff, nb);
  scan3_kernel<<<nb, 256, 0, stream>>>(off, boff, N);
  place_kernel<<<(E + 255) / 256, 256, 0, stream>>>(ei, off, cursor, csr, csre, E);
  gather_ea_kernel<<<(N + 15) / 16, 256, 0, stream>>>(ea, off, csre, S_ea, N);
  embed_kernel<<<(N + 255) / 256, 256, 0, stream>>>(x, Wemb, h, N);

  int nchunk = (N + 31) / 32;
  for (int l = 0; l < L; ++l) {
    aggregate_ea_kernel<<<(N + 3) / 4, 256, 0, stream>>>(
        h, off, csr, S_ea, We + (size_t)l * EMB * BONDF, be + (size_t)l * EMB,
        aggr16, N);
    mlp_mfma_kernel<<<(nchunk + 3) / 4, 256, 0, stream>>>(
        aggr16, W1b + (size_t)l * HID * EMB, W2b + (size_t)l * HID * EMB,
        b1 + (size_t)l * HID, tmp, N);
    hipMemsetAsync(gsums, 0, 2 * EMB * 4, stream);
    stats_kernel<<<512, 256, 0, stream>>>(tmp, gsums, N);
    float* outp = (l == L - 1) ? (float*)d_out : h;
    bn_kernel<<<(N * (EMB / 4) + 255) / 256, 256, 0, stream>>>(
        tmp, gsums, gamma + (size_t)l * EMB, beta + (size_t)l * EMB,
        outp, N, (l < L - 1) ? 1 : 0);
  }
}

// Round 10
// 733.990 us; speedup vs baseline: 1.6143x; 1.0503x over previous
//
#include <hip/hip_runtime.h>

#define EMB 64
#define HID 128
#define BONDF 16
#define ATOMF 32

typedef __attribute__((ext_vector_type(8))) short short8v;   // 8 bf16 (4 VGPRs)
typedef __attribute__((ext_vector_type(16))) float f32x16;   // MFMA 32x32 accum

__device__ __forceinline__ unsigned short f32_to_bf16_rne(float f) {
  unsigned u = __float_as_uint(f);
  u = (u + 0x7FFFu + ((u >> 16) & 1u)) >> 16;
  return (unsigned short)u;
}

// ---------------- embedding: h = x @ Wemb.T (fp32) ----------------
__global__ __launch_bounds__(256) void embed_kernel(
    const float* __restrict__ x, const float* __restrict__ Wemb,
    float* __restrict__ h, int N)
{
  __shared__ float sW[EMB * ATOMF];
  int tid = threadIdx.x;
  for (int i = tid; i < EMB * ATOMF; i += 256) sW[i] = Wemb[i];
  __syncthreads();
  int row = blockIdx.x * 256 + tid;
  if (row >= N) return;
  float xin[ATOMF];
  const float4* xr = reinterpret_cast<const float4*>(x + (size_t)row * ATOMF);
#pragma unroll
  for (int k4 = 0; k4 < ATOMF / 4; ++k4) {
    float4 v = xr[k4];
    xin[4 * k4 + 0] = v.x; xin[4 * k4 + 1] = v.y;
    xin[4 * k4 + 2] = v.z; xin[4 * k4 + 3] = v.w;
  }
  float4* hr = reinterpret_cast<float4*>(h + (size_t)row * EMB);
  for (int o4 = 0; o4 < EMB / 4; ++o4) {
    float acc[4];
#pragma unroll
    for (int c = 0; c < 4; ++c) {
      const float* wrow = sW + (o4 * 4 + c) * ATOMF;
      float a = 0.f;
#pragma unroll
      for (int kk = 0; kk < ATOMF / 4; ++kk) {
        float4 w = reinterpret_cast<const float4*>(wrow)[kk];
        a = fmaf(w.x, xin[4 * kk + 0], a);
        a = fmaf(w.y, xin[4 * kk + 1], a);
        a = fmaf(w.z, xin[4 * kk + 2], a);
        a = fmaf(w.w, xin[4 * kk + 3], a);
      }
      acc[c] = a;
    }
    hr[o4] = make_float4(acc[0], acc[1], acc[2], acc[3]);
  }
}

// ------------- fp32 -> bf16 weight conversion (once/call) -------------
__global__ __launch_bounds__(256) void cvt_bf16_kernel(
    const float* __restrict__ s, unsigned short* __restrict__ d, int n)
{
  int i = blockIdx.x * 256 + threadIdx.x;
  if (i < n) d[i] = f32_to_bf16_rne(s[i]);
}

// ------------- degree histogram -------------
__global__ __launch_bounds__(256) void deg_kernel(
    const int* __restrict__ ei, int* __restrict__ deg, int E)
{
  int e = blockIdx.x * 256 + threadIdx.x;
  if (e < E) atomicAdd(&deg[ei[E + e]], 1);
}

// ------------- hierarchical scan -------------
__global__ __launch_bounds__(256) void scan1_kernel(
    const int* __restrict__ deg, int* __restrict__ off,
    int* __restrict__ bsum, int n)
{
  __shared__ int ws[4];
  int tid = threadIdx.x, lane = tid & 63, wid = tid >> 6;
  int i = blockIdx.x * 256 + tid;
  int v = (i < n) ? deg[i] : 0;
  int x = v;
#pragma unroll
  for (int d = 1; d < 64; d <<= 1) {
    int t = __shfl_up(x, d, 64);
    if (lane >= d) x += t;
  }
  if (lane == 63) ws[wid] = x;
  __syncthreads();
  int add = 0;
  for (int w = 0; w < wid; ++w) add += ws[w];
  if (i < n) off[i] = x + add - v;
  if (tid == 255) bsum[blockIdx.x] = x + add;
}

__global__ __launch_bounds__(256) void scan_small_kernel(
    const int* __restrict__ deg, int* __restrict__ off, int n)
{
  __shared__ int warpsums[4];
  __shared__ int s_carry;
  int tid = threadIdx.x, lane = tid & 63, wid = tid >> 6;
  if (tid == 0) s_carry = 0;
  __syncthreads();
  for (int base = 0; base < n; base += 256) {
    int i = base + tid;
    int v = (i < n) ? deg[i] : 0;
    int x = v;
#pragma unroll
    for (int d = 1; d < 64; d <<= 1) {
      int t = __shfl_up(x, d, 64);
      if (lane >= d) x += t;
    }
    if (lane == 63) warpsums[wid] = x;
    __syncthreads();
    int wsum = 0;
    for (int w = 0; w < wid; ++w) wsum += warpsums[w];
    int incl = x + wsum + s_carry;
    if (i < n) off[i] = incl - v;
    __syncthreads();
    if (tid == 255) s_carry = incl;
    __syncthreads();
  }
  if (tid == 0) off[n] = s_carry;
}

__global__ __launch_bounds__(256) void scan3_kernel(
    int* __restrict__ off, const int* __restrict__ boff, int n)
{
  int i = blockIdx.x * 256 + threadIdx.x;
  if (i < n) off[i] += boff[blockIdx.x];
  if (i == 0) off[n] = boff[gridDim.x];
}

// ------------- place edges into CSR slots (packed src+eid, one 8B store) -------------
__global__ __launch_bounds__(256) void place_kernel(
    const int* __restrict__ ei, const int* __restrict__ off,
    int* __restrict__ cursor, int2* __restrict__ csr_packed, int E)
{
  int e = blockIdx.x * 256 + threadIdx.x;
  if (e >= E) return;
  int d = ei[E + e];
  int pos = atomicAdd(&cursor[d], 1);
  csr_packed[off[d] + pos] = make_int2(ei[e], e);  // (src, eid) in one line-dirty
}

// ------------- S_ea[i] = sum_{e->i} edge_attr[e] -------------
__global__ __launch_bounds__(256) void gather_ea_kernel(
    const float* __restrict__ ea, const int* __restrict__ off,
    const int2* __restrict__ csr_packed, float* __restrict__ S_ea, int N)
{
  int f = threadIdx.x & 15;
  int node = blockIdx.x * 16 + (threadIdx.x >> 4);
  if (node >= N) return;
  float acc = 0.f;
  int s0 = off[node], s1 = off[node + 1];
  for (int e = s0; e < s1; ++e)
    acc += ea[(size_t)csr_packed[e].y * BONDF + f];
  S_ea[(size_t)node * BONDF + f] = acc;
}

// ------------- aggregate + edge-emb term, emit bf16 -------------
// 8 row-loads in flight; edge summation order unchanged (sequential e).
__global__ __launch_bounds__(256) void aggregate_ea_kernel(
    const float* __restrict__ h, const int* __restrict__ off,
    const int2* __restrict__ csr_packed, const float* __restrict__ S_ea,
    const float* __restrict__ We_l, const float* __restrict__ be_l,
    unsigned short* __restrict__ aggr16, int N)
{
  __shared__ float sWet[BONDF * EMB];  // transposed: [f][k]
  __shared__ float sbe[EMB];
  int tid = threadIdx.x;
  for (int i = tid; i < EMB * BONDF; i += 256) {
    int k = i >> 4, f = i & 15;
    sWet[f * EMB + k] = We_l[i];
  }
  if (tid < EMB) sbe[tid] = be_l[tid];
  __syncthreads();
  int lane = tid & 63;
  int node = blockIdx.x * 4 + (tid >> 6);
  if (node >= N) return;
  float acc = h[(size_t)node * EMB + lane];  // self loop
  int s0 = off[node], s1 = off[node + 1];
  int e = s0;
  // peel to even e (16B-aligned int4 over int2 pairs)
  if (e < s1 && (e & 1)) {
    acc += h[(size_t)csr_packed[e].x * EMB + lane];
    ++e;
  }
  // 8 independent row loads in flight per iteration
  for (; e + 7 < s1; e += 8) {
    int4 p0 = *reinterpret_cast<const int4*>(csr_packed + e);      // e, e+1
    int4 p1 = *reinterpret_cast<const int4*>(csr_packed + e + 2);  // e+2, e+3
    int4 p2 = *reinterpret_cast<const int4*>(csr_packed + e + 4);
    int4 p3 = *reinterpret_cast<const int4*>(csr_packed + e + 6);
    float v0 = h[(size_t)p0.x * EMB + lane];
    float v1 = h[(size_t)p0.z * EMB + lane];
    float v2 = h[(size_t)p1.x * EMB + lane];
    float v3 = h[(size_t)p1.z * EMB + lane];
    float v4 = h[(size_t)p2.x * EMB + lane];
    float v5 = h[(size_t)p2.z * EMB + lane];
    float v6 = h[(size_t)p3.x * EMB + lane];
    float v7 = h[(size_t)p3.z * EMB + lane];
    acc += v0; acc += v1; acc += v2; acc += v3;
    acc += v4; acc += v5; acc += v6; acc += v7;
  }
  for (; e + 1 < s1; e += 2) {
    int4 p = *reinterpret_cast<const int4*>(csr_packed + e);
    float v0 = h[(size_t)p.x * EMB + lane];
    float v1 = h[(size_t)p.z * EMB + lane];
    acc += v0; acc += v1;
  }
  if (e < s1) acc += h[(size_t)csr_packed[e].x * EMB + lane];
  float dp1 = (float)(s1 - s0) + 1.0f;
  acc = fmaf(sbe[lane], dp1, acc);
  const float* sea = S_ea + (size_t)node * BONDF;
#pragma unroll
  for (int f = 0; f < BONDF; ++f)
    acc = fmaf(sWet[f * EMB + lane], sea[f], acc);
  aggr16[(size_t)node * EMB + lane] = f32_to_bf16_rne(acc);
}

// ------------- MFMA MLP: tmp[32-row chunk] = W2·relu(W1·in^T + b1) (^T) -------------
__global__ __launch_bounds__(256) void mlp_mfma_kernel(
    const unsigned short* __restrict__ aggr16,  // [N][64] bf16
    const unsigned short* __restrict__ W1b,     // [128][64] bf16
    const unsigned short* __restrict__ W2b,     // [64][128] bf16
    const float* __restrict__ b1,               // [128]
    float* __restrict__ tmp, int N)
{
  int wid = threadIdx.x >> 6;
  int lane = threadIdx.x & 63;
  int chunk = blockIdx.x * 4 + wid;
  int row0 = chunk * 32;
  if (row0 >= N) return;
  int col = lane & 31;
  int g = lane >> 5;
  int row = row0 + col;
  int rowc = min(row, N - 1);

  f32x16 acc1[4] = {};
#pragma unroll
  for (int kt = 0; kt < 4; ++kt) {
    short8v bfrag = *reinterpret_cast<const short8v*>(
        aggr16 + (size_t)rowc * EMB + kt * 16 + g * 8);
#pragma unroll
    for (int mt = 0; mt < 4; ++mt) {
      short8v afrag = *reinterpret_cast<const short8v*>(
          W1b + (size_t)(mt * 32 + col) * EMB + kt * 16 + g * 8);
      acc1[mt] = __builtin_amdgcn_mfma_f32_32x32x16_bf16(afrag, bfrag, acc1[mt], 0, 0, 0);
    }
  }

  unsigned u[32];
#pragma unroll
  for (int t = 0; t < 16; ++t) {
    const int mt = t >> 2, q = t & 3;
    float v0 = fmaxf(acc1[mt][4 * q + 0] + b1[mt * 32 + 8 * q + 4 * g + 0], 0.f);
    float v1 = fmaxf(acc1[mt][4 * q + 1] + b1[mt * 32 + 8 * q + 4 * g + 1], 0.f);
    float v2 = fmaxf(acc1[mt][4 * q + 2] + b1[mt * 32 + 8 * q + 4 * g + 2], 0.f);
    float v3 = fmaxf(acc1[mt][4 * q + 3] + b1[mt * 32 + 8 * q + 4 * g + 3], 0.f);
    asm("v_cvt_pk_bf16_f32 %0, %1, %2" : "=v"(u[2 * t + 0]) : "v"(v0), "v"(v1));
    asm("v_cvt_pk_bf16_f32 %0, %1, %2" : "=v"(u[2 * t + 1]) : "v"(v2), "v"(v3));
  }

  short8v b2f[8];
#pragma unroll
  for (int kt2 = 0; kt2 < 8; ++kt2) {
    unsigned e0 = u[4 * kt2 + 0], e1 = u[4 * kt2 + 1];
    unsigned o0 = u[4 * kt2 + 2], o1 = u[4 * kt2 + 3];
    unsigned pe0 = (unsigned)__shfl_xor((int)e0, 32, 64);
    unsigned pe1 = (unsigned)__shfl_xor((int)e1, 32, 64);
    unsigned po0 = (unsigned)__shfl_xor((int)o0, 32, 64);
    unsigned po1 = (unsigned)__shfl_xor((int)o1, 32, 64);
    union { unsigned w[4]; short8v v; } cvt;
    cvt.w[0] = (g == 0) ? e0 : po0;
    cvt.w[1] = (g == 0) ? e1 : po1;
    cvt.w[2] = (g == 0) ? pe0 : o0;
    cvt.w[3] = (g == 0) ? pe1 : o1;
    b2f[kt2] = cvt.v;
  }

  f32x16 acc2[2] = {};
#pragma unroll
  for (int kt2 = 0; kt2 < 8; ++kt2) {
#pragma unroll
    for (int mt2 = 0; mt2 < 2; ++mt2) {
      short8v a2 = *reinterpret_cast<const short8v*>(
          W2b + (size_t)(mt2 * 32 + col) * HID + kt2 * 16 + g * 8);
      acc2[mt2] = __builtin_amdgcn_mfma_f32_32x32x16_bf16(a2, b2f[kt2], acc2[mt2], 0, 0, 0);
    }
  }

  if (row < N) {
#pragma unroll
    for (int mt2 = 0; mt2 < 2; ++mt2)
#pragma unroll
      for (int r = 0; r < 16; ++r) {
        int o = mt2 * 32 + (r & 3) + 8 * (r >> 2) + 4 * g;
        tmp[(size_t)row * EMB + o] = acc2[mt2][r];
      }
  }
}

// ------------- per-layer column stats (sum, sumsq) -------------
__global__ __launch_bounds__(256) void stats_kernel(
    const float* __restrict__ tmp, float* __restrict__ gsums, int N)
{
  __shared__ float sh[256], sh2[256];
  int tid = threadIdx.x;
  int c = tid & 63, rg = tid >> 6;
  float s = 0.f, s2 = 0.f;
  for (int r = blockIdx.x * 4 + rg; r < N; r += gridDim.x * 4) {
    float v = tmp[(size_t)r * EMB + c];
    s += v; s2 += v * v;
  }
  sh[tid] = s; sh2[tid] = s2;
  __syncthreads();
  if (tid < 64) {
    s = sh[tid] + sh[tid + 64] + sh[tid + 128] + sh[tid + 192];
    s2 = sh2[tid] + sh2[tid + 64] + sh2[tid + 128] + sh2[tid + 192];
    atomicAdd(&gsums[c], s);
    atomicAdd(&gsums[EMB + c], s2);
  }
}

// ------------- per-layer BN + (mish) -------------
__global__ __launch_bounds__(256) void bn_kernel(
    const float* __restrict__ tmp, const float* __restrict__ gsums,
    const float* __restrict__ gamma, const float* __restrict__ beta,
    float* __restrict__ out, int N, int apply_mish)
{
  int idx = blockIdx.x * 256 + threadIdx.x;
  int total = N * (EMB / 4);
  if (idx >= total) return;
  int c4 = idx & (EMB / 4 - 1);
  float invN = 1.0f / (float)N;
  float4 v = reinterpret_cast<const float4*>(tmp)[idx];
  float o[4] = {v.x, v.y, v.z, v.w};
#pragma unroll
  for (int c = 0; c < 4; ++c) {
    int col = c4 * 4 + c;
    float mu = gsums[col] * invN;
    float var = gsums[EMB + col] * invN - mu * mu;
    float sc = gamma[col] * rsqrtf(var + 1e-5f);
    float shf = beta[col] - mu * sc;
    float y = o[c] * sc + shf;
    if (apply_mish) {
      float sp = (y > 20.f) ? y : log1pf(expf(y));
      y = y * tanhf(sp);
    }
    o[c] = y;
  }
  reinterpret_cast<float4*>(out)[idx] = make_float4(o[0], o[1], o[2], o[3]);
}

extern "C" void kernel_launch(void* const* d_in, const int* in_sizes, int n_in,
                              void* d_out, int out_size, void* d_ws, size_t ws_size,
                              hipStream_t stream) {
  (void)n_in; (void)out_size; (void)ws_size;
  const float* x     = (const float*)d_in[0];
  const float* ea    = (const float*)d_in[1];
  const float* Wemb  = (const float*)d_in[2];
  const float* W1    = (const float*)d_in[3];
  const float* b1    = (const float*)d_in[4];
  const float* W2    = (const float*)d_in[5];
  const float* We    = (const float*)d_in[7];
  const float* be    = (const float*)d_in[8];
  const float* gamma = (const float*)d_in[9];
  const float* beta  = (const float*)d_in[10];
  const int*   ei    = (const int*)d_in[11];

  int N = in_sizes[0] / ATOMF;
  int E = in_sizes[11] / 2;
  int L = in_sizes[3] / (HID * EMB);

  char* w = (char*)d_ws;
  auto alloc = [&](size_t bytes) {
    void* p = (void*)w;
    w += (bytes + 255) & ~(size_t)255;
    return p;
  };
  float*          h      = (float*)alloc((size_t)N * EMB * 4);
  float*          tmp    = (float*)alloc((size_t)N * EMB * 4);
  unsigned short* aggr16 = (unsigned short*)alloc((size_t)N * EMB * 2);
  float*          S_ea   = (float*)alloc((size_t)N * BONDF * 4);
  int*            deg    = (int*)alloc((size_t)N * 4);
  int*            off    = (int*)alloc((size_t)(N + 1) * 4);
  int*            cursor = (int*)alloc((size_t)N * 4);
  int2*           csrp   = (int2*)alloc((size_t)E * 8);
  int*            bsum   = (int*)alloc(1024 * 4);
  int*            boff   = (int*)alloc(1025 * 4);
  float*          gsums  = (float*)alloc(2 * EMB * 4);
  unsigned short* W1b    = (unsigned short*)alloc((size_t)L * HID * EMB * 2);
  unsigned short* W2b    = (unsigned short*)alloc((size_t)L * HID * EMB * 2);

  hipMemsetAsync(deg, 0, (size_t)N * 4, stream);
  hipMemsetAsync(cursor, 0, (size_t)N * 4, stream);

  int nW = L * HID * EMB;
  cvt_bf16_kernel<<<(nW + 255) / 256, 256, 0, stream>>>(W1, W1b, nW);
  cvt_bf16_kernel<<<(nW + 255) / 256, 256, 0, stream>>>(W2, W2b, nW);

  int nb = (N + 255) / 256;
  deg_kernel<<<(E + 255) / 256, 256, 0, stream>>>(ei, deg, E);
  scan1_kernel<<<nb, 256, 0, stream>>>(deg, off, bsum, N);
  scan_small_kernel<<<1, 256, 0, stream>>>(bsum, boff, nb);
  scan3_kernel<<<nb, 256, 0, stream>>>(off, boff, N);
  place_kernel<<<(E + 255) / 256, 256, 0, stream>>>(ei, off, cursor, csrp, E);
  gather_ea_kernel<<<(N + 15) / 16, 256, 0, stream>>>(ea, off, csrp, S_ea, N);
  embed_kernel<<<(N + 255) / 256, 256, 0, stream>>>(x, Wemb, h, N);

  int nchunk = (N + 31) / 32;
  for (int l = 0; l < L; ++l) {
    aggregate_ea_kernel<<<(N + 3) / 4, 256, 0, stream>>>(
        h, off, csrp, S_ea, We + (size_t)l * EMB * BONDF, be + (size_t)l * EMB,
        aggr16, N);
    mlp_mfma_kernel<<<(nchunk + 3) / 4, 256, 0, stream>>>(
        aggr16, W1b + (size_t)l * HID * EMB, W2b + (size_t)l * HID * EMB,
        b1 + (size_t)l * HID, tmp, N);
    hipMemsetAsync(gsums, 0, 2 * EMB * 4, stream);
    stats_kernel<<<512, 256, 0, stream>>>(tmp, gsums, N);
    float* outp = (l == L - 1) ? (float*)d_out : h;
    bn_kernel<<<(N * (EMB / 4) + 255) / 256, 256, 0, stream>>>(
        tmp, gsums, gamma + (size_t)l * EMB, beta + (size_t)l * EMB,
        outp, N, (l < L - 1) ? 1 : 0);
  }
}